// Round 1
// baseline (45.478 us; speedup 1.0000x reference)
//
#include <hip/hip_runtime.h>

// out[b,t,c] = (x[b,t,c] > 0) ? emb1[c] : emb0[c]
// The reference's 4-bit pack/unpack is an identity round-trip; this is a
// pure elementwise select, HBM-bound (~268 MB traffic/call).

__global__ __launch_bounds__(256) void rosa_select_kernel(
    const float4* __restrict__ x,
    const float4* __restrict__ e0,
    const float4* __restrict__ e1,
    float4* __restrict__ out,
    int n_vec,      // total float4 elements = B*T*C/4
    int cmask)      // (C/4 - 1), C/4 assumed power of two (1024/4 = 256)
{
    const int tid    = blockIdx.x * blockDim.x + threadIdx.x;
    const int stride = gridDim.x * blockDim.x;

    // stride (2048*256 = 524288) is a multiple of C/4 (256), so the channel
    // index is invariant across this thread's grid-stride iterations: hoist
    // the emb loads out of the loop.
    const int c = tid & cmask;
    const float4 a = e0[c];
    const float4 b = e1[c];

    for (int v = tid; v < n_vec; v += stride) {
        const float4 xv = x[v];
        float4 o;
        o.x = xv.x > 0.0f ? b.x : a.x;
        o.y = xv.y > 0.0f ? b.y : a.y;
        o.z = xv.z > 0.0f ? b.z : a.z;
        o.w = xv.w > 0.0f ? b.w : a.w;
        out[v] = o;
    }
}

extern "C" void kernel_launch(void* const* d_in, const int* in_sizes, int n_in,
                              void* d_out, int out_size, void* d_ws, size_t ws_size,
                              hipStream_t stream) {
    const float4* x  = (const float4*)d_in[0];
    const float4* e0 = (const float4*)d_in[1];
    const float4* e1 = (const float4*)d_in[2];
    float4* out      = (float4*)d_out;

    const int n_vec = out_size / 4;          // 33,554,432 / 4 = 8,388,608
    const int cvec  = in_sizes[1] / 4;       // C/4 = 256 (power of two)
    const int cmask = cvec - 1;

    const int block = 256;
    const int grid  = 2048;                  // 256 CU x 8 blocks/CU; grid-stride the rest

    rosa_select_kernel<<<grid, block, 0, stream>>>(x, e0, e1, out, n_vec, cmask);
}